// Round 6
// baseline (212.605 us; speedup 1.0000x reference)
//
#include <hip/hip_runtime.h>
#include <hip/hip_bf16.h>
#include <math.h>

// Problem constants
#define B_SZ   2
#define LSEQ   1024
#define DMODEL 1024
#define DSTATE 16
#define DCONV  4
#define DINNER 2048
#define MROWS  (B_SZ * LSEQ)        // 2048
#define NCHUNK 32
#define TCHUNK (LSEQ / NCHUNK)      // 32
#define NCAT   2176                 // 2048 (W_dt) + 32 (W_x) + 96 pad

typedef __attribute__((ext_vector_type(8))) short bf16x8;
typedef __attribute__((ext_vector_type(4))) float f32x4;

__device__ __forceinline__ void gl2lds16(const void* g, void* l) {
    __builtin_amdgcn_global_load_lds(
        (const __attribute__((address_space(1))) void*)g,
        (__attribute__((address_space(3))) void*)l, 16, 0, 0);
}

// ------------------------- fp32 -> bf16 conversion --------------------------
__global__ __launch_bounds__(256)
void cvt_bf16(const float* __restrict__ in, __hip_bfloat16* __restrict__ out)
{
    int i = (blockIdx.x * 256 + threadIdx.x) * 8;
    float4 a = *(const float4*)&in[i];
    float4 b = *(const float4*)&in[i + 4];
    union { __hip_bfloat16 h[8]; int4 v; } o;
    o.h[0] = __float2bfloat16(a.x); o.h[1] = __float2bfloat16(a.y);
    o.h[2] = __float2bfloat16(a.z); o.h[3] = __float2bfloat16(a.w);
    o.h[4] = __float2bfloat16(b.x); o.h[5] = __float2bfloat16(b.y);
    o.h[6] = __float2bfloat16(b.z); o.h[7] = __float2bfloat16(b.w);
    *(int4*)&out[i] = o.v;
}

// ------------- bf16 MFMA GEMM, triple-buffered counted-vmcnt ----------------
// C = A @ B^T.  A: M x K bf16, B: N x K bf16 (row-major), C fp32.
// Tile 128 x BN.  BN=128: 4 waves (2x2 of 64x64). BN=64: 2 waves (2x1).
// Every wave-tile is 64x64 = 16 MFMA consuming 8 LDS frags (0.5KB/MFMA).
// K-loop: 3 LDS buffers; per step: s_waitcnt vmcnt(NLD) (oldest stage landed,
// newer stages stay IN FLIGHT across the barrier), raw s_barrier, issue
// stage t+2 (into the buffer all waves finished reading at t-1), compute.
// Only the last step drains vmcnt(0).   (T3/T4, AITER-style never-drain)
// blockIdx.z picks C0/C1 (split-K partials).
// EPI 0: plain store. EPI 2: col<DINNER -> softplus(v+bias[col]) into C0;
//        col in [DINNER,DINNER+32) -> C2; else dropped.
template<int EPI, int BN>
__global__ __launch_bounds__((BN == 128) ? 256 : 128)
void gemm_bt(const __hip_bfloat16* __restrict__ A,
             const __hip_bfloat16* __restrict__ B,
             const float* __restrict__ bias,
             float* __restrict__ C0, float* __restrict__ C1,
             int ldc, float* __restrict__ C2,
             int K, int klen)
{
    constexpr int WAVES = (BN == 128) ? 4 : 2;
    constexpr int NCH   = (128 + BN) / 16;      // 1KB staging chunks per step
    constexpr int NLD   = NCH / WAVES;          // 4 (BN=128) or 6 (BN=64)
    constexpr int SMEL  = (128 + BN) * 32;      // bf16 elements per buffer
    __shared__ __hip_bfloat16 sm[3 * SMEL];

    const int tid  = threadIdx.x;
    const int lane = tid & 63;
    const int w    = tid >> 6;
    const int m0 = blockIdx.x * 128;
    const int n0 = blockIdx.y * BN;
    const int wr = (BN == 128) ? (w >> 1) : w;
    const int wc = (BN == 128) ? (w & 1)  : 0;
    const int kbase = blockIdx.z * klen;
    float* __restrict__ C = (blockIdx.z == 0) ? C0 : C1;

    // staging: chunk q = 16 rows x 64B of concatenated [A(128); B(BN)] tile
    const int lrow = lane >> 2;
    const int scol = (lane & 3) * 8;
    const __hip_bfloat16* srcp[NLD];
    #pragma unroll
    for (int i = 0; i < NLD; ++i) {
        const int q = w + WAVES * i;
        srcp[i] = (q < 8)
            ? A + (size_t)(m0 + q * 16 + lrow) * K + scol + kbase
            : B + (size_t)(n0 + (q - 8) * 16 + lrow) * K + scol + kbase;
    }

    f32x4 acc[4][4] = {};

    // prologue: stages 0 -> buf0, 1 -> buf1
    #pragma unroll
    for (int i = 0; i < NLD; ++i)
        gl2lds16(srcp[i], sm + (w + WAVES * i) * 512);
    #pragma unroll
    for (int i = 0; i < NLD; ++i)
        gl2lds16(srcp[i] + 32, sm + SMEL + (w + WAVES * i) * 512);

    const int nt = klen / 32;
    const int ar = (wr * 64 + (lane & 15)) * 32 + (lane >> 4) * 8;
    const int br = (wc * 64 + (lane & 15)) * 32 + (lane >> 4) * 8;

    auto compute = [&](int bufi) {
        const __hip_bfloat16* As = sm + bufi * SMEL;
        const __hip_bfloat16* Bs = As + 128 * 32;
        bf16x8 af[4], bfr[4];
        #pragma unroll
        for (int m = 0; m < 4; ++m)
            af[m] = *(const bf16x8*)&As[ar + m * 16 * 32];
        #pragma unroll
        for (int n = 0; n < 4; ++n)
            bfr[n] = *(const bf16x8*)&Bs[br + n * 16 * 32];
        #pragma unroll
        for (int m = 0; m < 4; ++m)
            #pragma unroll
            for (int n = 0; n < 4; ++n)
                acc[m][n] = __builtin_amdgcn_mfma_f32_16x16x32_bf16(
                    af[m], bfr[n], acc[m][n], 0, 0, 0);
    };

    int cb = 0;                                 // buffer being computed
    for (int t = 0; t < nt - 1; ++t) {
        if constexpr (NLD == 4)
            asm volatile("s_waitcnt vmcnt(4)" ::: "memory");
        else
            asm volatile("s_waitcnt vmcnt(6)" ::: "memory");
        __builtin_amdgcn_s_barrier();
        __builtin_amdgcn_sched_barrier(0);
        if (t + 2 < nt) {                       // stage t+2 into buf (t+2)%3
            int db = cb + 2; if (db >= 3) db -= 3;
            #pragma unroll
            for (int i = 0; i < NLD; ++i)
                gl2lds16(srcp[i] + (size_t)(t + 2) * 32,
                         sm + db * SMEL + (w + WAVES * i) * 512);
        }
        compute(cb);
        cb = (cb == 2) ? 0 : cb + 1;
    }
    asm volatile("s_waitcnt vmcnt(0)" ::: "memory");
    __builtin_amdgcn_s_barrier();
    __builtin_amdgcn_sched_barrier(0);
    compute(cb);

    #pragma unroll
    for (int m = 0; m < 4; ++m) {
        #pragma unroll
        for (int n = 0; n < 4; ++n) {
            const int col = n0 + wc * 64 + n * 16 + (lane & 15);
            #pragma unroll
            for (int j = 0; j < 4; ++j) {
                const int row = m0 + wr * 64 + m * 16 + (lane >> 4) * 4 + j;
                float v = acc[m][n][j];
                if (EPI == 0) {
                    C[(size_t)row * ldc + col] = v;
                } else {  // EPI == 2: fused dt + bc epilogue
                    if (col < DINNER) {
                        v += bias[col];
                        v = (v > 20.f) ? v : log1pf(__expf(v));
                        C0[(size_t)row * ldc + col] = v;
                    } else if (col < DINNER + 32) {
                        C2[(size_t)row * 32 + (col - DINNER)] = v;
                    }
                }
            }
        }
    }
}

// -------------------- split-K reduce: out = p0 + p1 -------------------------
__global__ __launch_bounds__(256)
void add2(const float* __restrict__ a, const float* __restrict__ b,
          float* __restrict__ o)
{
    int i = (blockIdx.x * 256 + threadIdx.x) * 4;
    float4 va = *(const float4*)&a[i];
    float4 vb = *(const float4*)&b[i];
    va.x += vb.x; va.y += vb.y; va.z += vb.z; va.w += vb.w;
    *(float4*)&o[i] = va;
}

// --------------- causal depthwise conv (k=4, left pad 3) + SiLU -------------
__global__ __launch_bounds__(256)
void conv_silu(const float* __restrict__ xz, const float* __restrict__ cw,
               const float* __restrict__ cb, float* __restrict__ u,
               __hip_bfloat16* __restrict__ u_bf)
{
    int idx = blockIdx.x * blockDim.x + threadIdx.x;
    int d = idx & (DINNER - 1);
    int m = idx >> 11;
    int t = m & (LSEQ - 1);
    float acc = cb[d];
    #pragma unroll
    for (int j = 0; j < DCONV; ++j) {
        int tt = t - (DCONV - 1) + j;
        if (tt >= 0)
            acc += xz[(size_t)(m - t + tt) * 4096 + d] * cw[d * DCONV + j];
    }
    float v = acc / (1.f + __expf(-acc));
    u[(size_t)m * DINNER + d] = v;
    u_bf[(size_t)m * DINNER + d] = __float2bfloat16(v);
}

// ------------------------- chunked selective scan ---------------------------
__global__ __launch_bounds__(256)
void scan_part1(const float* __restrict__ dt, const float* __restrict__ u,
                const float* __restrict__ bc, const float* __restrict__ A_log,
                float* __restrict__ s_end, float* __restrict__ dtsum)
{
    const int d = blockIdx.x * 256 + threadIdx.x;
    const int c = blockIdx.y;
    const int b = blockIdx.z;
    __shared__ float bcs[TCHUNK][32];
    {
        int f = threadIdx.x * 4;
        const float* src = bc + ((size_t)b * LSEQ + c * TCHUNK) * 32;
        *(float4*)&bcs[f >> 5][f & 31] = *(const float4*)&src[f];
    }
    float An[16];
    {
        float4 a0 = *(const float4*)&A_log[d * DSTATE + 0];
        float4 a1 = *(const float4*)&A_log[d * DSTATE + 4];
        float4 a2 = *(const float4*)&A_log[d * DSTATE + 8];
        float4 a3 = *(const float4*)&A_log[d * DSTATE + 12];
        An[0]=-__expf(a0.x); An[1]=-__expf(a0.y); An[2]=-__expf(a0.z); An[3]=-__expf(a0.w);
        An[4]=-__expf(a1.x); An[5]=-__expf(a1.y); An[6]=-__expf(a1.z); An[7]=-__expf(a1.w);
        An[8]=-__expf(a2.x); An[9]=-__expf(a2.y); An[10]=-__expf(a2.z); An[11]=-__expf(a2.w);
        An[12]=-__expf(a3.x); An[13]=-__expf(a3.y); An[14]=-__expf(a3.z); An[15]=-__expf(a3.w);
    }
    __syncthreads();
    const float* dtp = dt + ((size_t)b * LSEQ + c * TCHUNK) * DINNER + d;
    const float* up  = u  + ((size_t)b * LSEQ + c * TCHUNK) * DINNER + d;
    float s[16] = {};
    float sum = 0.f;
    for (int t = 0; t < TCHUNK; ++t) {
        float dtv = dtp[(size_t)t * DINNER];
        float uv  = up [(size_t)t * DINNER];
        sum += dtv;
        float du = dtv * uv;
        #pragma unroll
        for (int n = 0; n < 16; ++n) {
            float a = __expf(dtv * An[n]);
            s[n] = a * s[n] + du * bcs[t][n];
        }
    }
    float* se = s_end + ((size_t)(b * NCHUNK + c) * DINNER + d) * 16;
    #pragma unroll
    for (int q = 0; q < 4; ++q)
        *(float4*)&se[q * 4] = make_float4(s[q*4], s[q*4+1], s[q*4+2], s[q*4+3]);
    dtsum[(size_t)(b * NCHUNK + c) * DINNER + d] = sum;
}

// In-place combine: s_end[c] (chunk-local end state) -> state ENTERING chunk c.
__global__ __launch_bounds__(256)
void scan_combine(float* __restrict__ s_end, const float* __restrict__ dtsum,
                  const float* __restrict__ A_log)
{
    int idx = blockIdx.x * 256 + threadIdx.x;   // b*32768 + d*16 + n
    int n = idx & 15;
    int d = (idx >> 4) & (DINNER - 1);
    int b = idx >> 15;
    float An = -__expf(A_log[d * DSTATE + n]);
    float s = 0.f;
    for (int c = 0; c < NCHUNK; ++c) {
        size_t base = (size_t)(b * NCHUNK + c) * DINNER + d;
        float se = s_end[base * 16 + n];
        s_end[base * 16 + n] = s;
        float P = __expf(An * dtsum[base]);
        s = P * s + se;
    }
}

// Phase 3: local scan seeded with s_in; fuses y = sum_n s*C + D*u and the
// silu(z) gate; emits gated y as bf16.
__global__ __launch_bounds__(256)
void scan_part2(const float* __restrict__ dt, const float* __restrict__ u,
                const float* __restrict__ bc, const float* __restrict__ s_in,
                const float* __restrict__ A_log, const float* __restrict__ Dp,
                const float* __restrict__ xz, __hip_bfloat16* __restrict__ y_bf)
{
    const int d = blockIdx.x * 256 + threadIdx.x;
    const int c = blockIdx.y;
    const int b = blockIdx.z;
    __shared__ float bcs[TCHUNK][32];
    {
        int f = threadIdx.x * 4;
        const float* src = bc + ((size_t)b * LSEQ + c * TCHUNK) * 32;
        *(float4*)&bcs[f >> 5][f & 31] = *(const float4*)&src[f];
    }
    float An[16];
    {
        float4 a0 = *(const float4*)&A_log[d * DSTATE + 0];
        float4 a1 = *(const float4*)&A_log[d * DSTATE + 4];
        float4 a2 = *(const float4*)&A_log[d * DSTATE + 8];
        float4 a3 = *(const float4*)&A_log[d * DSTATE + 12];
        An[0]=-__expf(a0.x); An[1]=-__expf(a0.y); An[2]=-__expf(a0.z); An[3]=-__expf(a0.w);
        An[4]=-__expf(a1.x); An[5]=-__expf(a1.y); An[6]=-__expf(a1.z); An[7]=-__expf(a1.w);
        An[8]=-__expf(a2.x); An[9]=-__expf(a2.y); An[10]=-__expf(a2.z); An[11]=-__expf(a2.w);
        An[12]=-__expf(a3.x); An[13]=-__expf(a3.y); An[14]=-__expf(a3.z); An[15]=-__expf(a3.w);
    }
    float s[16];
    {
        const float* si = s_in + ((size_t)(b * NCHUNK + c) * DINNER + d) * 16;
        #pragma unroll
        for (int q = 0; q < 4; ++q) {
            float4 v = *(const float4*)&si[q * 4];
            s[q*4] = v.x; s[q*4+1] = v.y; s[q*4+2] = v.z; s[q*4+3] = v.w;
        }
    }
    const float Dd = Dp[d];
    __syncthreads();
    const float* dtp = dt + ((size_t)b * LSEQ + c * TCHUNK) * DINNER + d;
    const float* up  = u  + ((size_t)b * LSEQ + c * TCHUNK) * DINNER + d;
    const float* zp  = xz + ((size_t)b * LSEQ + c * TCHUNK) * 4096 + 2048 + d;
    __hip_bfloat16* yp = y_bf + ((size_t)b * LSEQ + c * TCHUNK) * DINNER + d;
    for (int t = 0; t < TCHUNK; ++t) {
        float dtv = dtp[(size_t)t * DINNER];
        float uv  = up [(size_t)t * DINNER];
        float du = dtv * uv;
        float y = Dd * uv;
        #pragma unroll
        for (int n = 0; n < 16; ++n) {
            float a = __expf(dtv * An[n]);
            s[n] = a * s[n] + du * bcs[t][n];
            y += s[n] * bcs[t][16 + n];
        }
        float zv = zp[(size_t)t * 4096];
        yp[(size_t)t * DINNER] = __float2bfloat16(y * (zv / (1.f + __expf(-zv))));
    }
}

// ---------------------------------------------------------------------------
extern "C" void kernel_launch(void* const* d_in, const int* in_sizes, int n_in,
                              void* d_out, int out_size, void* d_ws, size_t ws_size,
                              hipStream_t stream)
{
    const float* x      = (const float*)d_in[0];
    const float* W_in   = (const float*)d_in[1];
    const float* conv_w = (const float*)d_in[2];
    const float* conv_b = (const float*)d_in[3];
    const float* W_x    = (const float*)d_in[4];
    const float* W_dt   = (const float*)d_in[5];
    const float* b_dt   = (const float*)d_in[6];
    const float* A_log  = (const float*)d_in[7];
    const float* Dp     = (const float*)d_in[8];
    const float* W_out  = (const float*)d_in[9];
    float* out = (float*)d_out;

    const size_t MB = 1ull << 20;
    char* w8 = (char*)d_ws;
    float* xz    = (float*)(w8);              // 32MB  (2048 x 4096)
    float* u     = (float*)(w8 + 32*MB);      // 16MB
    float* dt    = (float*)(w8 + 48*MB);      // 16MB
    float* bc    = (float*)(w8 + 64*MB);      // 0.25MB
    float* sbuf  = (float*)(w8 + 65*MB);      // 8MB   s_end -> s_in (in place)
    float* dtsum = (float*)(w8 + 73*MB);      // 0.5MB
    __hip_bfloat16* u_bf   = (__hip_bfloat16*)(w8 + 74*MB);  // 8MB
    // region X (time-multiplexed):
    __hip_bfloat16* x_bf   = (__hip_bfloat16*)(w8 + 82*MB);  // 4MB   (GEMM1)
    __hip_bfloat16* Win_bf = (__hip_bfloat16*)(w8 + 86*MB);  // 8MB   (GEMM1)
    __hip_bfloat16* Wcat_bf= (__hip_bfloat16*)(w8 + 82*MB);  // 8.9MB (GEMM2)
    __hip_bfloat16* Wout_bf= (__hip_bfloat16*)(w8 + 91*MB);  // 4MB   (GEMM3)
    __hip_bfloat16* y_bf   = (__hip_bfloat16*)(w8 + 82*MB);  // 8MB   (GEMM3)
    // split-K partials for GEMM3: reuse xz region (dead after scan_part2)
    float* p0 = (float*)(w8);                 // 8MB
    float* p1 = (float*)(w8 + 8*MB);          // 8MB

    // 0. convert GEMM1 inputs
    cvt_bf16<<<(MROWS * DMODEL) / (256 * 8), 256, 0, stream>>>(x, x_bf);
    cvt_bf16<<<(4096 * DMODEL) / (256 * 8), 256, 0, stream>>>(W_in, Win_bf);
    // 1. xz = x @ W_in.T           (M=2048, N=4096, K=1024)
    gemm_bt<0, 128><<<dim3(16, 32, 1), 256, 0, stream>>>(
        x_bf, Win_bf, nullptr, xz, xz, 4096, nullptr, DMODEL, DMODEL);
    // 2. u = silu(causal_conv(xi) + conv_b)  (+ bf16 copy)
    conv_silu<<<(MROWS * DINNER) / 256, 256, 0, stream>>>(xz, conv_w, conv_b, u, u_bf);
    // 2b. build Wcat = [W_dt; W_x] bf16 (pad rows' columns never written), Wout
    cvt_bf16<<<(DINNER * DINNER) / (256 * 8), 256, 0, stream>>>(W_dt, Wcat_bf);
    cvt_bf16<<<(32 * DINNER) / (256 * 8), 256, 0, stream>>>(W_x, Wcat_bf + (size_t)DINNER * DINNER);
    cvt_bf16<<<(DMODEL * DINNER) / (256 * 8), 256, 0, stream>>>(W_out, Wout_bf);
    // 3. fused: dt = softplus(u@W_dt.T + b_dt), bc = u@W_x.T  (N=2176)
    gemm_bt<2, 64><<<dim3(16, NCAT / 64, 1), 128, 0, stream>>>(
        u_bf, Wcat_bf, b_dt, dt, dt, DINNER, bc, DINNER, DINNER);
    // 4. chunked scan (writes gated y as bf16)
    scan_part1<<<dim3(DINNER/256, NCHUNK, B_SZ), 256, 0, stream>>>(
        dt, u, bc, A_log, sbuf, dtsum);
    scan_combine<<<(B_SZ * DINNER * DSTATE) / 256, 256, 0, stream>>>(
        sbuf, dtsum, A_log);
    scan_part2<<<dim3(DINNER/256, NCHUNK, B_SZ), 256, 0, stream>>>(
        dt, u, bc, sbuf, A_log, Dp, xz, y_bf);
    // 5. out = y @ W_out.T  (M=2048, N=1024, K=2048), split-K=2 over xz region
    gemm_bt<0, 64><<<dim3(16, 16, 2), 128, 0, stream>>>(
        y_bf, Wout_bf, nullptr, p0, p1, DMODEL, nullptr, DINNER, DINNER / 2);
    add2<<<(MROWS * DMODEL) / (256 * 4), 256, 0, stream>>>(p0, p1, out);
}

// Round 7
// 195.621 us; speedup vs baseline: 1.0868x; 1.0868x over previous
//
#include <hip/hip_runtime.h>
#include <hip/hip_bf16.h>
#include <math.h>

// Problem constants
#define B_SZ   2
#define LSEQ   1024
#define DMODEL 1024
#define DSTATE 16
#define DCONV  4
#define DINNER 2048
#define MROWS  (B_SZ * LSEQ)        // 2048
#define NCHUNK 32
#define TCHUNK (LSEQ / NCHUNK)      // 32
#define NCAT   2176                 // 2048 (W_dt) + 32 (W_x) + 96 pad

typedef __attribute__((ext_vector_type(8))) short bf16x8;
typedef __attribute__((ext_vector_type(4))) float f32x4;

__device__ __forceinline__ void gl2lds16(const void* g, void* l) {
    __builtin_amdgcn_global_load_lds(
        (const __attribute__((address_space(1))) void*)g,
        (__attribute__((address_space(3))) void*)l, 16, 0, 0);
}

// ------------------------- fp32 -> bf16 conversion --------------------------
__global__ __launch_bounds__(256)
void cvt_bf16(const float* __restrict__ in, __hip_bfloat16* __restrict__ out)
{
    int i = (blockIdx.x * 256 + threadIdx.x) * 8;
    float4 a = *(const float4*)&in[i];
    float4 b = *(const float4*)&in[i + 4];
    union { __hip_bfloat16 h[8]; int4 v; } o;
    o.h[0] = __float2bfloat16(a.x); o.h[1] = __float2bfloat16(a.y);
    o.h[2] = __float2bfloat16(a.z); o.h[3] = __float2bfloat16(a.w);
    o.h[4] = __float2bfloat16(b.x); o.h[5] = __float2bfloat16(b.y);
    o.h[6] = __float2bfloat16(b.z); o.h[7] = __float2bfloat16(b.w);
    *(int4*)&out[i] = o.v;
}

// -------- bf16 MFMA GEMM, 4-buffer depth-3 counted-vmcnt pipeline -----------
// C = A @ B^T.  A: M x K bf16, B: N x K bf16 (row-major), C fp32.
// Tile 128 x BN, always 256 threads / 4 waves as 2x2; wave tile 64 x BN/2.
// K-loop: 4 LDS buffers, 3 stages prefetched ahead. Iter t: vmcnt(2*NLD)
// (stage t landed; t+1,t+2 stay IN FLIGHT across the barrier), s_barrier,
// issue stage t+3 into buf (t+3)&3 (drained since barrier t proves compute
// t-1 done), compute buf t&3. Tail: vmcnt 2NLD -> NLD -> 0.
// blockIdx.z picks C0/C1 (split-K partials).
// EPI 0: plain store. EPI 2: col<DINNER -> softplus(v+bias[col]) into C0;
//        col in [DINNER,DINNER+32) -> C2; else dropped.
template<int EPI, int BN>
__global__ __launch_bounds__(256)
void gemm_bt(const __hip_bfloat16* __restrict__ A,
             const __hip_bfloat16* __restrict__ B,
             const float* __restrict__ bias,
             float* __restrict__ C0, float* __restrict__ C1,
             int ldc, float* __restrict__ C2,
             int K, int klen)
{
    constexpr int NFR  = BN / 32;               // B-frags per wave (4 or 2)
    constexpr int NCH  = (128 + BN) / 16;       // 1KB staging chunks per stage
    constexpr int NLD  = NCH / 4;               // chunks per wave (4 or 3)
    constexpr int SMEL = (128 + BN) * 32;       // bf16 elements per buffer
    __shared__ __hip_bfloat16 sm[4 * SMEL];

    const int tid  = threadIdx.x;
    const int lane = tid & 63;
    const int w    = tid >> 6;
    const int m0 = blockIdx.x * 128;
    const int n0 = blockIdx.y * BN;
    const int wr = w >> 1, wc = w & 1;
    const int kbase = blockIdx.z * klen;
    float* __restrict__ C = (blockIdx.z == 0) ? C0 : C1;

    // staging: chunk q = 16 rows x 64B of concatenated [A(128); B(BN)] tile
    const int lrow = lane >> 2;
    const int scol = (lane & 3) * 8;
    const __hip_bfloat16* srcp[NLD];
    #pragma unroll
    for (int i = 0; i < NLD; ++i) {
        const int q = w + 4 * i;
        srcp[i] = (q < 8)
            ? A + (size_t)(m0 + q * 16 + lrow) * K + scol + kbase
            : B + (size_t)(n0 + (q - 8) * 16 + lrow) * K + scol + kbase;
    }

    f32x4 acc[4][NFR] = {};

    // prologue: stages 0,1,2 -> bufs 0,1,2
    #pragma unroll
    for (int s = 0; s < 3; ++s)
        #pragma unroll
        for (int i = 0; i < NLD; ++i)
            gl2lds16(srcp[i] + (size_t)s * 32, sm + s * SMEL + (w + 4 * i) * 512);

    const int nt = klen / 32;                   // >= 3 always here
    const int ar = (wr * 64 + (lane & 15)) * 32 + (lane >> 4) * 8;
    const int br = (wc * (BN / 2) + (lane & 15)) * 32 + (lane >> 4) * 8;

    for (int t = 0; t < nt; ++t) {
        const int rem = nt - 1 - t;             // stages still to land after t
        if (rem >= 2) {
            if constexpr (NLD == 3) asm volatile("s_waitcnt vmcnt(6)" ::: "memory");
            else                    asm volatile("s_waitcnt vmcnt(8)" ::: "memory");
        } else if (rem == 1) {
            if constexpr (NLD == 3) asm volatile("s_waitcnt vmcnt(3)" ::: "memory");
            else                    asm volatile("s_waitcnt vmcnt(4)" ::: "memory");
        } else {
            asm volatile("s_waitcnt vmcnt(0)" ::: "memory");
        }
        __builtin_amdgcn_s_barrier();
        __builtin_amdgcn_sched_barrier(0);
        if (t + 3 < nt) {                       // stage t+3 into buf (t+3)&3
            const int db = (t + 3) & 3;
            #pragma unroll
            for (int i = 0; i < NLD; ++i)
                gl2lds16(srcp[i] + (size_t)(t + 3) * 32,
                         sm + db * SMEL + (w + 4 * i) * 512);
        }
        __builtin_amdgcn_sched_barrier(0);
        const __hip_bfloat16* As = sm + (t & 3) * SMEL;
        const __hip_bfloat16* Bs = As + 128 * 32;
        bf16x8 af[4], bfr[NFR];
        #pragma unroll
        for (int m = 0; m < 4; ++m)
            af[m] = *(const bf16x8*)&As[ar + m * 16 * 32];
        #pragma unroll
        for (int n = 0; n < NFR; ++n)
            bfr[n] = *(const bf16x8*)&Bs[br + n * 16 * 32];
        #pragma unroll
        for (int m = 0; m < 4; ++m)
            #pragma unroll
            for (int n = 0; n < NFR; ++n)
                acc[m][n] = __builtin_amdgcn_mfma_f32_16x16x32_bf16(
                    af[m], bfr[n], acc[m][n], 0, 0, 0);
    }

    #pragma unroll
    for (int m = 0; m < 4; ++m) {
        #pragma unroll
        for (int n = 0; n < NFR; ++n) {
            const int col = n0 + wc * (BN / 2) + n * 16 + (lane & 15);
            #pragma unroll
            for (int j = 0; j < 4; ++j) {
                const int row = m0 + wr * 64 + m * 16 + (lane >> 4) * 4 + j;
                float v = acc[m][n][j];
                if (EPI == 0) {
                    C[(size_t)row * ldc + col] = v;
                } else {  // EPI == 2: fused dt + bc epilogue
                    if (col < DINNER) {
                        v += bias[col];
                        v = (v > 20.f) ? v : log1pf(__expf(v));
                        C0[(size_t)row * ldc + col] = v;
                    } else if (col < DINNER + 32) {
                        C2[(size_t)row * 32 + (col - DINNER)] = v;
                    }
                }
            }
        }
    }
}

// -------------------- split-K reduce: out = p0 + p1 -------------------------
__global__ __launch_bounds__(256)
void add2(const float* __restrict__ a, const float* __restrict__ b,
          float* __restrict__ o)
{
    int i = (blockIdx.x * 256 + threadIdx.x) * 4;
    float4 va = *(const float4*)&a[i];
    float4 vb = *(const float4*)&b[i];
    va.x += vb.x; va.y += vb.y; va.z += vb.z; va.w += vb.w;
    *(float4*)&o[i] = va;
}

// --------------- causal depthwise conv (k=4, left pad 3) + SiLU -------------
__global__ __launch_bounds__(256)
void conv_silu(const float* __restrict__ xz, const float* __restrict__ cw,
               const float* __restrict__ cb, float* __restrict__ u,
               __hip_bfloat16* __restrict__ u_bf)
{
    int idx = blockIdx.x * blockDim.x + threadIdx.x;
    int d = idx & (DINNER - 1);
    int m = idx >> 11;
    int t = m & (LSEQ - 1);
    float acc = cb[d];
    #pragma unroll
    for (int j = 0; j < DCONV; ++j) {
        int tt = t - (DCONV - 1) + j;
        if (tt >= 0)
            acc += xz[(size_t)(m - t + tt) * 4096 + d] * cw[d * DCONV + j];
    }
    float v = acc / (1.f + __expf(-acc));
    u[(size_t)m * DINNER + d] = v;
    u_bf[(size_t)m * DINNER + d] = __float2bfloat16(v);
}

// ------------------------- chunked selective scan ---------------------------
__global__ __launch_bounds__(256)
void scan_part1(const float* __restrict__ dt, const float* __restrict__ u,
                const float* __restrict__ bc, const float* __restrict__ A_log,
                float* __restrict__ s_end, float* __restrict__ dtsum)
{
    const int d = blockIdx.x * 256 + threadIdx.x;
    const int c = blockIdx.y;
    const int b = blockIdx.z;
    __shared__ float bcs[TCHUNK][32];
    {
        int f = threadIdx.x * 4;
        const float* src = bc + ((size_t)b * LSEQ + c * TCHUNK) * 32;
        *(float4*)&bcs[f >> 5][f & 31] = *(const float4*)&src[f];
    }
    float An[16];
    {
        float4 a0 = *(const float4*)&A_log[d * DSTATE + 0];
        float4 a1 = *(const float4*)&A_log[d * DSTATE + 4];
        float4 a2 = *(const float4*)&A_log[d * DSTATE + 8];
        float4 a3 = *(const float4*)&A_log[d * DSTATE + 12];
        An[0]=-__expf(a0.x); An[1]=-__expf(a0.y); An[2]=-__expf(a0.z); An[3]=-__expf(a0.w);
        An[4]=-__expf(a1.x); An[5]=-__expf(a1.y); An[6]=-__expf(a1.z); An[7]=-__expf(a1.w);
        An[8]=-__expf(a2.x); An[9]=-__expf(a2.y); An[10]=-__expf(a2.z); An[11]=-__expf(a2.w);
        An[12]=-__expf(a3.x); An[13]=-__expf(a3.y); An[14]=-__expf(a3.z); An[15]=-__expf(a3.w);
    }
    __syncthreads();
    const float* dtp = dt + ((size_t)b * LSEQ + c * TCHUNK) * DINNER + d;
    const float* up  = u  + ((size_t)b * LSEQ + c * TCHUNK) * DINNER + d;
    float s[16] = {};
    float sum = 0.f;
    for (int t = 0; t < TCHUNK; ++t) {
        float dtv = dtp[(size_t)t * DINNER];
        float uv  = up [(size_t)t * DINNER];
        sum += dtv;
        float du = dtv * uv;
        #pragma unroll
        for (int n = 0; n < 16; ++n) {
            float a = __expf(dtv * An[n]);
            s[n] = a * s[n] + du * bcs[t][n];
        }
    }
    float* se = s_end + ((size_t)(b * NCHUNK + c) * DINNER + d) * 16;
    #pragma unroll
    for (int q = 0; q < 4; ++q)
        *(float4*)&se[q * 4] = make_float4(s[q*4], s[q*4+1], s[q*4+2], s[q*4+3]);
    dtsum[(size_t)(b * NCHUNK + c) * DINNER + d] = sum;
}

// In-place combine: s_end[c] (chunk-local end state) -> state ENTERING chunk c.
__global__ __launch_bounds__(256)
void scan_combine(float* __restrict__ s_end, const float* __restrict__ dtsum,
                  const float* __restrict__ A_log)
{
    int idx = blockIdx.x * 256 + threadIdx.x;   // b*32768 + d*16 + n
    int n = idx & 15;
    int d = (idx >> 4) & (DINNER - 1);
    int b = idx >> 15;
    float An = -__expf(A_log[d * DSTATE + n]);
    float s = 0.f;
    for (int c = 0; c < NCHUNK; ++c) {
        size_t base = (size_t)(b * NCHUNK + c) * DINNER + d;
        float se = s_end[base * 16 + n];
        s_end[base * 16 + n] = s;
        float P = __expf(An * dtsum[base]);
        s = P * s + se;
    }
}

// Phase 3: local scan seeded with s_in; fuses y = sum_n s*C + D*u and the
// silu(z) gate; emits gated y as bf16.
__global__ __launch_bounds__(256)
void scan_part2(const float* __restrict__ dt, const float* __restrict__ u,
                const float* __restrict__ bc, const float* __restrict__ s_in,
                const float* __restrict__ A_log, const float* __restrict__ Dp,
                const float* __restrict__ xz, __hip_bfloat16* __restrict__ y_bf)
{
    const int d = blockIdx.x * 256 + threadIdx.x;
    const int c = blockIdx.y;
    const int b = blockIdx.z;
    __shared__ float bcs[TCHUNK][32];
    {
        int f = threadIdx.x * 4;
        const float* src = bc + ((size_t)b * LSEQ + c * TCHUNK) * 32;
        *(float4*)&bcs[f >> 5][f & 31] = *(const float4*)&src[f];
    }
    float An[16];
    {
        float4 a0 = *(const float4*)&A_log[d * DSTATE + 0];
        float4 a1 = *(const float4*)&A_log[d * DSTATE + 4];
        float4 a2 = *(const float4*)&A_log[d * DSTATE + 8];
        float4 a3 = *(const float4*)&A_log[d * DSTATE + 12];
        An[0]=-__expf(a0.x); An[1]=-__expf(a0.y); An[2]=-__expf(a0.z); An[3]=-__expf(a0.w);
        An[4]=-__expf(a1.x); An[5]=-__expf(a1.y); An[6]=-__expf(a1.z); An[7]=-__expf(a1.w);
        An[8]=-__expf(a2.x); An[9]=-__expf(a2.y); An[10]=-__expf(a2.z); An[11]=-__expf(a2.w);
        An[12]=-__expf(a3.x); An[13]=-__expf(a3.y); An[14]=-__expf(a3.z); An[15]=-__expf(a3.w);
    }
    float s[16];
    {
        const float* si = s_in + ((size_t)(b * NCHUNK + c) * DINNER + d) * 16;
        #pragma unroll
        for (int q = 0; q < 4; ++q) {
            float4 v = *(const float4*)&si[q * 4];
            s[q*4] = v.x; s[q*4+1] = v.y; s[q*4+2] = v.z; s[q*4+3] = v.w;
        }
    }
    const float Dd = Dp[d];
    __syncthreads();
    const float* dtp = dt + ((size_t)b * LSEQ + c * TCHUNK) * DINNER + d;
    const float* up  = u  + ((size_t)b * LSEQ + c * TCHUNK) * DINNER + d;
    const float* zp  = xz + ((size_t)b * LSEQ + c * TCHUNK) * 4096 + 2048 + d;
    __hip_bfloat16* yp = y_bf + ((size_t)b * LSEQ + c * TCHUNK) * DINNER + d;
    for (int t = 0; t < TCHUNK; ++t) {
        float dtv = dtp[(size_t)t * DINNER];
        float uv  = up [(size_t)t * DINNER];
        float du = dtv * uv;
        float y = Dd * uv;
        #pragma unroll
        for (int n = 0; n < 16; ++n) {
            float a = __expf(dtv * An[n]);
            s[n] = a * s[n] + du * bcs[t][n];
            y += s[n] * bcs[t][16 + n];
        }
        float zv = zp[(size_t)t * 4096];
        yp[(size_t)t * DINNER] = __float2bfloat16(y * (zv / (1.f + __expf(-zv))));
    }
}

// ---------------------------------------------------------------------------
extern "C" void kernel_launch(void* const* d_in, const int* in_sizes, int n_in,
                              void* d_out, int out_size, void* d_ws, size_t ws_size,
                              hipStream_t stream)
{
    const float* x      = (const float*)d_in[0];
    const float* W_in   = (const float*)d_in[1];
    const float* conv_w = (const float*)d_in[2];
    const float* conv_b = (const float*)d_in[3];
    const float* W_x    = (const float*)d_in[4];
    const float* W_dt   = (const float*)d_in[5];
    const float* b_dt   = (const float*)d_in[6];
    const float* A_log  = (const float*)d_in[7];
    const float* Dp     = (const float*)d_in[8];
    const float* W_out  = (const float*)d_in[9];
    float* out = (float*)d_out;

    const size_t MB = 1ull << 20;
    char* w8 = (char*)d_ws;
    float* xz    = (float*)(w8);              // 32MB  (2048 x 4096)
    float* u     = (float*)(w8 + 32*MB);      // 16MB
    float* dt    = (float*)(w8 + 48*MB);      // 16MB
    float* bc    = (float*)(w8 + 64*MB);      // 0.25MB
    float* sbuf  = (float*)(w8 + 65*MB);      // 8MB   s_end -> s_in (in place)
    float* dtsum = (float*)(w8 + 73*MB);      // 0.5MB
    __hip_bfloat16* u_bf   = (__hip_bfloat16*)(w8 + 74*MB);  // 8MB
    // region X (time-multiplexed):
    __hip_bfloat16* x_bf   = (__hip_bfloat16*)(w8 + 82*MB);  // 4MB   (GEMM1)
    __hip_bfloat16* Win_bf = (__hip_bfloat16*)(w8 + 86*MB);  // 8MB   (GEMM1)
    __hip_bfloat16* Wcat_bf= (__hip_bfloat16*)(w8 + 82*MB);  // 8.9MB (GEMM2)
    __hip_bfloat16* Wout_bf= (__hip_bfloat16*)(w8 + 91*MB);  // 4MB   (GEMM3)
    __hip_bfloat16* y_bf   = (__hip_bfloat16*)(w8 + 82*MB);  // 8MB   (GEMM3)
    // split-K partials for GEMM3: reuse xz region (dead after scan_part2)
    float* p0 = (float*)(w8);                 // 8MB
    float* p1 = (float*)(w8 + 8*MB);          // 8MB

    // 0. convert GEMM1 inputs
    cvt_bf16<<<(MROWS * DMODEL) / (256 * 8), 256, 0, stream>>>(x, x_bf);
    cvt_bf16<<<(4096 * DMODEL) / (256 * 8), 256, 0, stream>>>(W_in, Win_bf);
    // 1. xz = x @ W_in.T           (M=2048, N=4096, K=1024)
    gemm_bt<0, 128><<<dim3(16, 32, 1), 256, 0, stream>>>(
        x_bf, Win_bf, nullptr, xz, xz, 4096, nullptr, DMODEL, DMODEL);
    // 2. u = silu(causal_conv(xi) + conv_b)  (+ bf16 copy)
    conv_silu<<<(MROWS * DINNER) / 256, 256, 0, stream>>>(xz, conv_w, conv_b, u, u_bf);
    // 2b. build Wcat = [W_dt; W_x] bf16 (pad rows' columns never written), Wout
    cvt_bf16<<<(DINNER * DINNER) / (256 * 8), 256, 0, stream>>>(W_dt, Wcat_bf);
    cvt_bf16<<<(32 * DINNER) / (256 * 8), 256, 0, stream>>>(W_x, Wcat_bf + (size_t)DINNER * DINNER);
    cvt_bf16<<<(DMODEL * DINNER) / (256 * 8), 256, 0, stream>>>(W_out, Wout_bf);
    // 3. fused: dt = softplus(u@W_dt.T + b_dt), bc = u@W_x.T  (N=2176)
    gemm_bt<2, 64><<<dim3(16, NCAT / 64, 1), 256, 0, stream>>>(
        u_bf, Wcat_bf, b_dt, dt, dt, DINNER, bc, DINNER, DINNER);
    // 4. chunked scan (writes gated y as bf16)
    scan_part1<<<dim3(DINNER/256, NCHUNK, B_SZ), 256, 0, stream>>>(
        dt, u, bc, A_log, sbuf, dtsum);
    scan_combine<<<(B_SZ * DINNER * DSTATE) / 256, 256, 0, stream>>>(
        sbuf, dtsum, A_log);
    scan_part2<<<dim3(DINNER/256, NCHUNK, B_SZ), 256, 0, stream>>>(
        dt, u, bc, sbuf, A_log, Dp, xz, y_bf);
    // 5. out = y @ W_out.T  (M=2048, N=1024, K=2048), split-K=2 over xz region
    gemm_bt<0, 64><<<dim3(16, 16, 2), 256, 0, stream>>>(
        y_bf, Wout_bf, nullptr, p0, p1, DMODEL, nullptr, DINNER, DINNER / 2);
    add2<<<(MROWS * DMODEL) / (256 * 4), 256, 0, stream>>>(p0, p1, out);
}

// Round 9
// 194.412 us; speedup vs baseline: 1.0936x; 1.0062x over previous
//
#include <hip/hip_runtime.h>
#include <hip/hip_bf16.h>
#include <math.h>

// Problem constants
#define B_SZ   2
#define LSEQ   1024
#define DMODEL 1024
#define DSTATE 16
#define DCONV  4
#define DINNER 2048
#define MROWS  (B_SZ * LSEQ)        // 2048
#define NCHUNK 32
#define TCHUNK (LSEQ / NCHUNK)      // 32
#define NCAT   2176                 // 2048 (W_dt) + 32 (W_x) + 96 pad
#define BKS    64                   // K-step

typedef __attribute__((ext_vector_type(8))) short bf16x8;
typedef __attribute__((ext_vector_type(4))) float f32x4;

__device__ __forceinline__ void gl2lds16(const void* g, void* l) {
    __builtin_amdgcn_global_load_lds(
        (const __attribute__((address_space(1))) void*)g,
        (__attribute__((address_space(3))) void*)l, 16, 0, 0);
}

// ------------------------- fp32 -> bf16 conversion --------------------------
__global__ __launch_bounds__(256)
void cvt_bf16(const float* __restrict__ in, __hip_bfloat16* __restrict__ out)
{
    int i = (blockIdx.x * 256 + threadIdx.x) * 8;
    float4 a = *(const float4*)&in[i];
    float4 b = *(const float4*)&in[i + 4];
    union { __hip_bfloat16 h[8]; int4 v; } o;
    o.h[0] = __float2bfloat16(a.x); o.h[1] = __float2bfloat16(a.y);
    o.h[2] = __float2bfloat16(a.z); o.h[3] = __float2bfloat16(a.w);
    o.h[4] = __float2bfloat16(b.x); o.h[5] = __float2bfloat16(b.y);
    o.h[6] = __float2bfloat16(b.z); o.h[7] = __float2bfloat16(b.w);
    *(int4*)&out[i] = o.v;
}

// ---------- bf16 MFMA GEMM: BM=128, BN=64, BK=64, swizzled LDS --------------
// C = A @ B^T (partial over [kbase, kbase+klen)).  4 waves as 2x2, wave tile
// 64x32 -> 16 MFMA/iter/wave.  LDS tiles [rows][64] bf16 (128B rows); slot s
// (16B) of row r holds global col16 (s ^ (r&7)).  Staging: gl2lds writes
// linearly; the SOURCE col is pre-swizzled (T2 both-sides rule). Reads XOR
// the slot with row&7 -> balanced across all 32 banks.
// 2 LDS buffers (48KB): stage(t+1) -> compute(t) -> drain+barrier.
// EPI 0: plain store into Cbase + blockIdx.z*pstride (split-K partials).
// EPI 2: col<DINNER -> softplus(v+bias[col]) into C; [DINNER,DINNER+32) -> C2.
template<int EPI>
__global__ __launch_bounds__(256)
void gemm_bt(const __hip_bfloat16* __restrict__ A,
             const __hip_bfloat16* __restrict__ B,
             const float* __restrict__ bias,
             float* __restrict__ Cbase, size_t pstride, int ldc,
             float* __restrict__ C2,
             int K, int klen)
{
    constexpr int BN   = 64;
    constexpr int NLD  = (128 + BN) / 8 / 4;     // 6 chunks per wave
    constexpr int SMEL = (128 + BN) * BKS;       // 12288 bf16 per buffer
    __shared__ __hip_bfloat16 sm[2 * SMEL];

    const int tid  = threadIdx.x;
    const int lane = tid & 63;
    const int w    = tid >> 6;
    const int m0 = blockIdx.x * 128;
    const int n0 = blockIdx.y * BN;
    const int wr = w >> 1, wc = w & 1;
    const int kbase = blockIdx.z * klen;
    float* __restrict__ C = Cbase + (size_t)blockIdx.z * pstride;

    // staging: chunk q = 8 rows x 128B. lane -> row q*8 + (lane>>3),
    // LDS slot (lane&7); source col16 pre-swizzled = (lane&7) ^ (lane>>3).
    const int lrow = lane >> 3;
    const int swc  = ((lane & 7) ^ lrow) * 8;    // element col in stage
    const __hip_bfloat16* srcp[NLD];
    #pragma unroll
    for (int i = 0; i < NLD; ++i) {
        const int q = w + 4 * i;                 // 0..23
        srcp[i] = (q < 16)
            ? A + (size_t)(m0 + q * 8 + lrow) * K + kbase + swc
            : B + (size_t)(n0 + (q - 16) * 8 + lrow) * K + kbase + swc;
    }

    f32x4 acc[4][2] = {};
    const int l7 = lane & 7, l15 = lane & 15, lq = lane >> 4;
    const int sw0 = (lq ^ l7) * 8;               // slot holding col16 lq
    const int sw1 = sw0 ^ 32;                    // slot holding col16 lq+4

    // prologue: stage 0 -> buf0, drain, barrier
    #pragma unroll
    for (int i = 0; i < NLD; ++i)
        gl2lds16(srcp[i], sm + (w + 4 * i) * 512);
    asm volatile("s_waitcnt vmcnt(0)" ::: "memory");
    __builtin_amdgcn_s_barrier();
    __builtin_amdgcn_sched_barrier(0);

    const int nt = klen / BKS;
    int buf = 0;
    for (int t = 0; t < nt; ++t) {
        if (t + 1 < nt) {                        // stage next early
            #pragma unroll
            for (int i = 0; i < NLD; ++i)
                gl2lds16(srcp[i] + (size_t)(t + 1) * BKS,
                         sm + (buf ^ 1) * SMEL + (w + 4 * i) * 512);
        }
        const __hip_bfloat16* As = sm + buf * SMEL;
        const __hip_bfloat16* Bs = As + 128 * BKS;
        bf16x8 a0[4], a1[4], b0[2], b1[2];
        #pragma unroll
        for (int m = 0; m < 4; ++m) {
            const int r = (wr * 64 + m * 16 + l15) * BKS;
            a0[m] = *(const bf16x8*)&As[r + sw0];
            a1[m] = *(const bf16x8*)&As[r + sw1];
        }
        #pragma unroll
        for (int n = 0; n < 2; ++n) {
            const int r = (wc * 32 + n * 16 + l15) * BKS;
            b0[n] = *(const bf16x8*)&Bs[r + sw0];
            b1[n] = *(const bf16x8*)&Bs[r + sw1];
        }
        #pragma unroll
        for (int m = 0; m < 4; ++m)
            #pragma unroll
            for (int n = 0; n < 2; ++n) {
                acc[m][n] = __builtin_amdgcn_mfma_f32_16x16x32_bf16(
                    a0[m], b0[n], acc[m][n], 0, 0, 0);
                acc[m][n] = __builtin_amdgcn_mfma_f32_16x16x32_bf16(
                    a1[m], b1[n], acc[m][n], 0, 0, 0);
            }
        asm volatile("s_waitcnt vmcnt(0)" ::: "memory");
        __builtin_amdgcn_s_barrier();
        __builtin_amdgcn_sched_barrier(0);
        buf ^= 1;
    }

    #pragma unroll
    for (int m = 0; m < 4; ++m)
        #pragma unroll
        for (int n = 0; n < 2; ++n) {
            const int col = n0 + wc * 32 + n * 16 + l15;
            #pragma unroll
            for (int j = 0; j < 4; ++j) {
                const int row = m0 + wr * 64 + m * 16 + lq * 4 + j;
                float v = acc[m][n][j];
                if (EPI == 0) {
                    C[(size_t)row * ldc + col] = v;
                } else {  // EPI == 2: fused dt + bc epilogue
                    if (col < DINNER) {
                        v += bias[col];
                        v = (v > 20.f) ? v : log1pf(__expf(v));
                        C[(size_t)row * ldc + col] = v;
                    } else if (col < DINNER + 32) {
                        C2[(size_t)row * 32 + (col - DINNER)] = v;
                    }
                }
            }
        }
}

// ------------------ GEMM3 split-K=4 reduce: out = sum of 4 ------------------
__global__ __launch_bounds__(256)
void add4(const float* __restrict__ p, float* __restrict__ o)
{
    const size_t S = (size_t)MROWS * DMODEL;
    int i = (blockIdx.x * 256 + threadIdx.x) * 4;
    float4 a = *(const float4*)&p[i];
    float4 b = *(const float4*)&p[i + S];
    float4 c = *(const float4*)&p[i + 2 * S];
    float4 d = *(const float4*)&p[i + 3 * S];
    a.x += b.x + c.x + d.x; a.y += b.y + c.y + d.y;
    a.z += b.z + c.z + d.z; a.w += b.w + c.w + d.w;
    *(float4*)&o[i] = a;
}

// --------------- causal depthwise conv (k=4, left pad 3) + SiLU -------------
__global__ __launch_bounds__(256)
void conv_silu(const float* __restrict__ xz, const float* __restrict__ cw,
               const float* __restrict__ cb, float* __restrict__ u,
               __hip_bfloat16* __restrict__ u_bf)
{
    int idx = blockIdx.x * blockDim.x + threadIdx.x;
    int d = idx & (DINNER - 1);
    int m = idx >> 11;
    int t = m & (LSEQ - 1);
    float acc = cb[d];
    #pragma unroll
    for (int j = 0; j < DCONV; ++j) {
        int tt = t - (DCONV - 1) + j;
        if (tt >= 0)
            acc += xz[(size_t)(m - t + tt) * 4096 + d] * cw[d * DCONV + j];
    }
    float v = acc / (1.f + __expf(-acc));
    u[(size_t)m * DINNER + d] = v;
    u_bf[(size_t)m * DINNER + d] = __float2bfloat16(v);
}

// ------------------------- chunked selective scan ---------------------------
__global__ __launch_bounds__(256)
void scan_part1(const float* __restrict__ dt, const float* __restrict__ u,
                const float* __restrict__ bc, const float* __restrict__ A_log,
                float* __restrict__ s_end, float* __restrict__ dtsum)
{
    const int d = blockIdx.x * 256 + threadIdx.x;
    const int c = blockIdx.y;
    const int b = blockIdx.z;
    __shared__ float bcs[TCHUNK][32];
    {
        int f = threadIdx.x * 4;
        const float* src = bc + ((size_t)b * LSEQ + c * TCHUNK) * 32;
        *(float4*)&bcs[f >> 5][f & 31] = *(const float4*)&src[f];
    }
    float An[16];
    {
        float4 a0 = *(const float4*)&A_log[d * DSTATE + 0];
        float4 a1 = *(const float4*)&A_log[d * DSTATE + 4];
        float4 a2 = *(const float4*)&A_log[d * DSTATE + 8];
        float4 a3 = *(const float4*)&A_log[d * DSTATE + 12];
        An[0]=-__expf(a0.x); An[1]=-__expf(a0.y); An[2]=-__expf(a0.z); An[3]=-__expf(a0.w);
        An[4]=-__expf(a1.x); An[5]=-__expf(a1.y); An[6]=-__expf(a1.z); An[7]=-__expf(a1.w);
        An[8]=-__expf(a2.x); An[9]=-__expf(a2.y); An[10]=-__expf(a2.z); An[11]=-__expf(a2.w);
        An[12]=-__expf(a3.x); An[13]=-__expf(a3.y); An[14]=-__expf(a3.z); An[15]=-__expf(a3.w);
    }
    __syncthreads();
    const float* dtp = dt + ((size_t)b * LSEQ + c * TCHUNK) * DINNER + d;
    const float* up  = u  + ((size_t)b * LSEQ + c * TCHUNK) * DINNER + d;
    float s[16] = {};
    float sum = 0.f;
    for (int t = 0; t < TCHUNK; ++t) {
        float dtv = dtp[(size_t)t * DINNER];
        float uv  = up [(size_t)t * DINNER];
        sum += dtv;
        float du = dtv * uv;
        #pragma unroll
        for (int n = 0; n < 16; ++n) {
            float a = __expf(dtv * An[n]);
            s[n] = a * s[n] + du * bcs[t][n];
        }
    }
    float* se = s_end + ((size_t)(b * NCHUNK + c) * DINNER + d) * 16;
    #pragma unroll
    for (int q = 0; q < 4; ++q)
        *(float4*)&se[q * 4] = make_float4(s[q*4], s[q*4+1], s[q*4+2], s[q*4+3]);
    dtsum[(size_t)(b * NCHUNK + c) * DINNER + d] = sum;
}

// In-place combine: s_end[c] (chunk-local end state) -> state ENTERING chunk c.
__global__ __launch_bounds__(256)
void scan_combine(float* __restrict__ s_end, const float* __restrict__ dtsum,
                  const float* __restrict__ A_log)
{
    int idx = blockIdx.x * 256 + threadIdx.x;   // b*32768 + d*16 + n
    int n = idx & 15;
    int d = (idx >> 4) & (DINNER - 1);
    int b = idx >> 15;
    float An = -__expf(A_log[d * DSTATE + n]);
    float s = 0.f;
    for (int c = 0; c < NCHUNK; ++c) {
        size_t base = (size_t)(b * NCHUNK + c) * DINNER + d;
        float se = s_end[base * 16 + n];
        s_end[base * 16 + n] = s;
        float P = __expf(An * dtsum[base]);
        s = P * s + se;
    }
}

// Phase 3: local scan seeded with s_in; fuses y = sum_n s*C + D*u and the
// silu(z) gate; emits gated y as bf16.
__global__ __launch_bounds__(256)
void scan_part2(const float* __restrict__ dt, const float* __restrict__ u,
                const float* __restrict__ bc, const float* __restrict__ s_in,
                const float* __restrict__ A_log, const float* __restrict__ Dp,
                const float* __restrict__ xz, __hip_bfloat16* __restrict__ y_bf)
{
    const int d = blockIdx.x * 256 + threadIdx.x;
    const int c = blockIdx.y;
    const int b = blockIdx.z;
    __shared__ float bcs[TCHUNK][32];
    {
        int f = threadIdx.x * 4;
        const float* src = bc + ((size_t)b * LSEQ + c * TCHUNK) * 32;
        *(float4*)&bcs[f >> 5][f & 31] = *(const float4*)&src[f];
    }
    float An[16];
    {
        float4 a0 = *(const float4*)&A_log[d * DSTATE + 0];
        float4 a1 = *(const float4*)&A_log[d * DSTATE + 4];
        float4 a2 = *(const float4*)&A_log[d * DSTATE + 8];
        float4 a3 = *(const float4*)&A_log[d * DSTATE + 12];
        An[0]=-__expf(a0.x); An[1]=-__expf(a0.y); An[2]=-__expf(a0.z); An[3]=-__expf(a0.w);
        An[4]=-__expf(a1.x); An[5]=-__expf(a1.y); An[6]=-__expf(a1.z); An[7]=-__expf(a1.w);
        An[8]=-__expf(a2.x); An[9]=-__expf(a2.y); An[10]=-__expf(a2.z); An[11]=-__expf(a2.w);
        An[12]=-__expf(a3.x); An[13]=-__expf(a3.y); An[14]=-__expf(a3.z); An[15]=-__expf(a3.w);
    }
    float s[16];
    {
        const float* si = s_in + ((size_t)(b * NCHUNK + c) * DINNER + d) * 16;
        #pragma unroll
        for (int q = 0; q < 4; ++q) {
            float4 v = *(const float4*)&si[q * 4];
            s[q*4] = v.x; s[q*4+1] = v.y; s[q*4+2] = v.z; s[q*4+3] = v.w;
        }
    }
    const float Dd = Dp[d];
    __syncthreads();
    const float* dtp = dt + ((size_t)b * LSEQ + c * TCHUNK) * DINNER + d;
    const float* up  = u  + ((size_t)b * LSEQ + c * TCHUNK) * DINNER + d;
    const float* zp  = xz + ((size_t)b * LSEQ + c * TCHUNK) * 4096 + 2048 + d;
    __hip_bfloat16* yp = y_bf + ((size_t)b * LSEQ + c * TCHUNK) * DINNER + d;
    for (int t = 0; t < TCHUNK; ++t) {
        float dtv = dtp[(size_t)t * DINNER];
        float uv  = up [(size_t)t * DINNER];
        float du = dtv * uv;
        float y = Dd * uv;
        #pragma unroll
        for (int n = 0; n < 16; ++n) {
            float a = __expf(dtv * An[n]);
            s[n] = a * s[n] + du * bcs[t][n];
            y += s[n] * bcs[t][16 + n];
        }
        float zv = zp[(size_t)t * 4096];
        yp[(size_t)t * DINNER] = __float2bfloat16(y * (zv / (1.f + __expf(-zv))));
    }
}

// ---------------------------------------------------------------------------
extern "C" void kernel_launch(void* const* d_in, const int* in_sizes, int n_in,
                              void* d_out, int out_size, void* d_ws, size_t ws_size,
                              hipStream_t stream)
{
    const float* x      = (const float*)d_in[0];
    const float* W_in   = (const float*)d_in[1];
    const float* conv_w = (const float*)d_in[2];
    const float* conv_b = (const float*)d_in[3];
    const float* W_x    = (const float*)d_in[4];
    const float* W_dt   = (const float*)d_in[5];
    const float* b_dt   = (const float*)d_in[6];
    const float* A_log  = (const float*)d_in[7];
    const float* Dp     = (const float*)d_in[8];
    const float* W_out  = (const float*)d_in[9];
    float* out = (float*)d_out;

    // Workspace map — HARD CEILING 94MB (95MB proven safe in round 7; the
    // 109MB map in round 8 overflowed ws and corrupted an input buffer).
    const size_t MB = 1ull << 20;
    char* w8 = (char*)d_ws;
    float* xz    = (float*)(w8);               // 0-32   | after scan: p3 (4x8MB)
    float* p3    = (float*)(w8);
    float* u     = (float*)(w8 + 32*MB);       // 32-48
    float* dtc   = (float*)(w8 + 48*MB);       // 48-64
    float* bc    = (float*)(w8 + 64*MB);       // 64-64.25
    float* sbuf  = (float*)(w8 + 65*MB);       // 65-73   s_end -> s_in in place
    float* dtsum = (float*)(w8 + 73*MB);       // 73-73.5
    __hip_bfloat16* u_bf   = (__hip_bfloat16*)(w8 + 74*MB); // 74-82
    // region X (82-94), time-multiplexed:
    __hip_bfloat16* x_bf   = (__hip_bfloat16*)(w8 + 82*MB); // 82-86  (GEMM1)
    __hip_bfloat16* Win_bf = (__hip_bfloat16*)(w8 + 86*MB); // 86-94  (GEMM1)
    __hip_bfloat16* Wcat_bf= (__hip_bfloat16*)(w8 + 82*MB); // 82-90.5 (GEMM2)
    __hip_bfloat16* Wout_bf= (__hip_bfloat16*)(w8 + 90*MB + 512*1024); // 90.5-94.5? no: 4MB -> 90.5-94.5 exceeds; use 82-86 after GEMM2?
    // NOTE: Wout_bf placed at 65MB region? sbuf needed through scan. Final:
    // Wout_bf shares region X tail only if it fits; instead put it at 48MB?
    // dtc needed through scan. Simplest safe spot: after GEMM2, Wcat is dead;
    // y_bf (82-90) and Wout_bf (90-94) both fit in region X.
    __hip_bfloat16* y_bf   = (__hip_bfloat16*)(w8 + 82*MB); // 82-90 (post-GEMM2)
    Wout_bf = (__hip_bfloat16*)(w8 + 90*MB);                // 90-94 (post-GEMM2)

    // 0. convert GEMM1 inputs
    cvt_bf16<<<(MROWS * DMODEL) / 2048, 256, 0, stream>>>(x, x_bf);
    cvt_bf16<<<(4096 * DMODEL) / 2048, 256, 0, stream>>>(W_in, Win_bf);
    // 1. xz = x @ W_in.T   (M=2048, N=4096, K=1024) — 1024 blocks
    gemm_bt<0><<<dim3(16, 64, 1), 256, 0, stream>>>(
        x_bf, Win_bf, nullptr, xz, 0, 4096, nullptr, DMODEL, DMODEL);
    // 2. u = silu(causal_conv(xi) + conv_b)  (+ bf16 copy)
    conv_silu<<<(MROWS * DINNER) / 256, 256, 0, stream>>>(xz, conv_w, conv_b, u, u_bf);
    // 2b. Wcat = [W_dt; W_x] bf16 into region X (x_bf/Win_bf dead).
    //     Pad rows 2080..2175 left as garbage — their output cols are dropped.
    cvt_bf16<<<(DINNER * DINNER) / 2048, 256, 0, stream>>>(W_dt, Wcat_bf);
    cvt_bf16<<<(32 * DINNER) / 2048, 256, 0, stream>>>(W_x, Wcat_bf + (size_t)DINNER * DINNER);
    // 3. fused GEMM2: dt = softplus(u@W_dt.T + b_dt), bc = u@W_x.T (N=2176)
    gemm_bt<2><<<dim3(16, NCAT / 64, 1), 256, 0, stream>>>(
        u_bf, Wcat_bf, b_dt, dtc, 0, DINNER, bc, DINNER, DINNER);
    // 3b. Wout bf16 (region X tail free after GEMM2)
    cvt_bf16<<<(DMODEL * DINNER) / 2048, 256, 0, stream>>>(W_out, Wout_bf);
    // 4. chunked scan (writes gated y as bf16 into region X head)
    scan_part1<<<dim3(DINNER/256, NCHUNK, B_SZ), 256, 0, stream>>>(
        dtc, u, bc, A_log, sbuf, dtsum);
    scan_combine<<<(B_SZ * DINNER * DSTATE) / 256, 256, 0, stream>>>(
        sbuf, dtsum, A_log);
    scan_part2<<<dim3(DINNER/256, NCHUNK, B_SZ), 256, 0, stream>>>(
        dtc, u, bc, sbuf, A_log, Dp, xz, y_bf);
    // 5. out = y @ W_out.T, split-K=4, partials over xz region (dead)
    gemm_bt<0><<<dim3(16, 16, 4), 256, 0, stream>>>(
        y_bf, Wout_bf, nullptr, p3, (size_t)MROWS * DMODEL, DMODEL, nullptr,
        DINNER, DINNER / 4);
    add4<<<(MROWS * DMODEL) / 1024, 256, 0, stream>>>(p3, out);
}